// Round 11
// baseline (332.602 us; speedup 1.0000x reference)
//
#include <hip/hip_runtime.h>
#include <hip/hip_bf16.h>

#define B_N 16
#define LP_N 1024
#define LQ_N 1024
#define H_N 1024

typedef unsigned short u16;
typedef __attribute__((ext_vector_type(8))) short bf16x8;
typedef __attribute__((ext_vector_type(4))) float f32x4;

__device__ __forceinline__ u16 f2bf(float x) {
    __hip_bfloat16 h = __float2bfloat16(x);
    return *(u16*)&h;
}
__device__ __forceinline__ float bf2f(u16 u) {
    __hip_bfloat16 h;
    *(u16*)&h = u;
    return __bfloat162float(h);
}

__device__ __forceinline__ void load_lds16(const u16* g, u16* l) {
    __builtin_amdgcn_global_load_lds(
        (const __attribute__((address_space(1))) void*)g,
        (__attribute__((address_space(3))) void*)l, 16, 0, 0);
}

#define MFMA_B16(a, b, c) __builtin_amdgcn_mfma_f32_16x16x32_bf16(a, b, c, 0, 0, 0)
#define VMW0()  asm volatile("s_waitcnt vmcnt(0)" ::: "memory")
#define LGKM0() asm volatile("s_waitcnt lgkmcnt(0)" ::: "memory")
#define SCHB()  __builtin_amdgcn_sched_barrier(0)
#define SBAR()  __builtin_amdgcn_s_barrier()

// ---------------------------------------------------------------------------
// 128x128 split-bf16 MFMA GEMM, NT form (R11).
// R10 post-mortem: 32x32 shape re-introduced 4-way conflicts -> reverted to
// the R9 16x16x32 kernel (0 conflicts). R3-R10 plateau at ~41% MfmaUtil with
// 1 block/CU (128KB LDS): at the per-tile gate+barrier the whole CU idles.
// Fix = occupancy structure, not schedule: 128x128 tile, 4 waves (2x2),
// BK=32 -> LDS 64KB split / 32KB dense -> 2 / ~4 blocks per CU, grid 1024.
// Co-resident blocks overlap each other's gate/LDS phases (m114 mechanism;
// m103: at the 2-barrier structure 128^2 (912 TF, ~3 blk/CU) > 256^2 (792)).
// All else identical to R9: {Ahi,Alo,Bhi,Blo} staged once per tile,
// T1=ah*bh, T2=ah*bl (reuses ah), T3=al*bh; one vmcnt(0)+s_barrier per
// tile; t+1 staged right after front reads; swizzle s_phys=s_log^((row>>1)&3)
// on pre-swizzled global source AND ds_read offsets (verified 0-conflict).
// DENSE=true: 2 regions, T1 only. EPI: 0=fp32, 1=+bias split bf16, 2=relu.
// ---------------------------------------------------------------------------
template<bool DENSE, int EPI>
__launch_bounds__(256, 2)
__global__ void gemm3t(const u16* __restrict__ Ahi, const u16* __restrict__ Alo,
                       const u16* __restrict__ Bhi, const u16* __restrict__ Blo,
                       const float* __restrict__ bias,
                       float* __restrict__ Cf, u16* __restrict__ Chi, u16* __restrict__ Clo,
                       int N, int gn, int gmn,
                       long long sA, long long sB, long long sC)
{
    constexpr int REG  = 4096;                   // u16 per 128x32 region (8KB)
    constexpr int NRG  = DENSE ? 2 : 4;          // [Ahi][Alo][Bhi][Blo] | [A][B]
    constexpr int BUF  = NRG * REG;
    constexpr int O_AL = REG;                    // split only
    constexpr int O_BH = DENSE ? REG : 2 * REG;
    constexpr int O_BL = 3 * REG;                // split only
    __shared__ __align__(16) u16 lds[2 * BUF];   // 64KB split / 32KB dense

    const int tid  = threadIdx.x;
    const int lane = tid & 63;
    const int wv   = tid >> 6;
    const int wr   = wv >> 1, wc = wv & 1;       // 2M x 2N waves, 64x64 each

    // XCD-contiguous block swizzle (nwg=1024 -> 128 contiguous tiles/XCD)
    const int d   = blockIdx.x;
    const int cpx = gridDim.x >> 3;
    const int swz = (d & 7) * cpx + (d >> 3);
    const long long z = swz / gmn;
    const int r_  = swz % gmn;
    const int bm  = (r_ / gn) * 128;
    const int bn  = (r_ % gn) * 128;

    const char* pAh = (const char*)(Ahi + z * sA);
    const char* pAl = (const char*)(Alo + z * sA);
    const char* pBh = (const char*)(Bhi + z * sB);
    const char* pBl = (const char*)(Blo + z * sB);

    // ---- staging: region = 512 x 16B chunks (128 rows x 4 slots); thread t
    // stages chunks {t, t+256} (rows r0, r0+64; same XOR since 64>>1=32,
    // 32&3=0). chunk c: row=c>>2, phys slot=c&3, src slot=(c&3)^((row>>1)&3).
    const int r0 = tid >> 2;                     // 0..63
    const int xc = (tid & 3) ^ ((r0 >> 1) & 3);
    const long long aof = (long long)(bm + r0) * 2048 + xc * 16;
    const long long bof = (long long)(bn + r0) * 2048 + xc * 16;
    const long long ao2 = aof + 64 * 2048;
    const long long bo2 = bof + 64 * 2048;
    const int d0 = tid * 8;                      // u16 dest offset (chunk t)
    const int d1 = d0 + 2048;                    // chunk t+256

    // ---- fragment ds_read offsets (u16 units within region), same swizzle
    int offA[4], offB[4];
#pragma unroll
    for (int i = 0; i < 4; ++i) {
        const int r = wr * 64 + i * 16 + (lane & 15);
        offA[i] = r * 32 + ((((lane >> 4) ^ (r >> 1)) & 3) << 3);
    }
#pragma unroll
    for (int j = 0; j < 4; ++j) {
        const int r = wc * 64 + j * 16 + (lane & 15);
        offB[j] = r * 32 + ((((lane >> 4) ^ (r >> 1)) & 3) << 3);
    }

    f32x4 acc[4][4];
#pragma unroll
    for (int i = 0; i < 4; ++i)
#pragma unroll
        for (int j = 0; j < 4; ++j)
            acc[i][j] = (f32x4){0.f, 0.f, 0.f, 0.f};

#define STG(NB, KB) do {                                                      \
        load_lds16((const u16*)(pAh + aof + (KB)), lds + (NB) + d0);          \
        load_lds16((const u16*)(pAh + ao2 + (KB)), lds + (NB) + d1);          \
        load_lds16((const u16*)(pBh + bof + (KB)), lds + (NB) + O_BH + d0);   \
        load_lds16((const u16*)(pBh + bo2 + (KB)), lds + (NB) + O_BH + d1);   \
        if constexpr (!DENSE) {                                               \
            load_lds16((const u16*)(pAl + aof + (KB)), lds + (NB) + O_AL + d0); \
            load_lds16((const u16*)(pAl + ao2 + (KB)), lds + (NB) + O_AL + d1); \
            load_lds16((const u16*)(pBl + bof + (KB)), lds + (NB) + O_BL + d0); \
            load_lds16((const u16*)(pBl + bo2 + (KB)), lds + (NB) + O_BL + d1); \
        }                                                                     \
    } while (0)

#define TERM(AF, BF) do {                                                     \
        __builtin_amdgcn_s_setprio(1);                                        \
        _Pragma("unroll")                                                     \
        for (int i = 0; i < 4; ++i)                                           \
            _Pragma("unroll")                                                 \
            for (int j = 0; j < 4; ++j)                                       \
                acc[i][j] = MFMA_B16(AF[i], BF[j], acc[i][j]);                \
        __builtin_amdgcn_s_setprio(0);                                        \
    } while (0)

    constexpr int NT = 32;                       // K=1024 / BK=32

    STG(0, 0);                                   // prologue: tile 0 -> buf 0

    for (int t = 0; t < NT; ++t) {
        const int cb = (t & 1) ? BUF : 0;
        const int nb = (t & 1) ? 0 : BUF;
        const long long kb = (long long)(t + 1) * 64;  // bytes

        VMW0();                  // tile t staged loads retired (per wave)
        SBAR();                  // cross-wave publish
        bf16x8 bh[4], bl[4], ah[4], al[4];
#pragma unroll
        for (int j = 0; j < 4; ++j) {
            bh[j] = *(const bf16x8*)(lds + cb + O_BH + offB[j]);
            if constexpr (!DENSE) bl[j] = *(const bf16x8*)(lds + cb + O_BL + offB[j]);
        }
#pragma unroll
        for (int i = 0; i < 4; ++i)
            ah[i] = *(const bf16x8*)(lds + cb + offA[i]);
        if (t + 1 < NT) STG(nb, kb);             // issue t+1 early (max slack)
        LGKM0(); SCHB();
        TERM(ah, bh);                            // T1: 16 MFMA
        if constexpr (!DENSE) {
#pragma unroll
            for (int i = 0; i < 4; ++i)
                al[i] = *(const bf16x8*)(lds + cb + O_AL + offA[i]);
            TERM(ah, bl);                        // T2 (al reads hide under T2)
            LGKM0(); SCHB();
            TERM(al, bh);                        // T3
        }
    }
#undef STG
#undef TERM

    // epilogue; C/D map: col = lane&15, row = (lane>>4)*4 + e  [m89/m91]
    const long long Cbase = z * sC;
#pragma unroll
    for (int i = 0; i < 4; ++i) {
        const int row0 = bm + wr * 64 + i * 16 + ((lane >> 4) << 2);
#pragma unroll
        for (int j = 0; j < 4; ++j) {
            const int col = bn + wc * 64 + j * 16 + (lane & 15);
#pragma unroll
            for (int e = 0; e < 4; ++e) {
                const float v = acc[i][j][e];
                const long long idx = Cbase + (long long)(row0 + e) * N + col;
                if constexpr (EPI == 0) {
                    Cf[idx] = v;
                } else if constexpr (EPI == 1) {
                    const float vb = v + bias[col];
                    const u16 h = f2bf(vb);
                    Chi[idx] = h;
                    Clo[idx] = f2bf(vb - bf2f(h));
                } else {
                    Cf[idx] = fmaxf(v, 0.f);
                }
            }
        }
    }
}

// fp32 -> bf16 hi/lo split, 4 elems/thread
__global__ void split_cvt(const float* __restrict__ in, u16* __restrict__ hi,
                          u16* __restrict__ lo, long long n4)
{
    const long long i = (long long)blockIdx.x * 256 + threadIdx.x;
    if (i >= n4) return;
    const float4 v = ((const float4*)in)[i];
    ushort4 h, l;
    h.x = f2bf(v.x); l.x = f2bf(v.x - bf2f(h.x));
    h.y = f2bf(v.y); l.y = f2bf(v.y - bf2f(h.y));
    h.z = f2bf(v.z); l.z = f2bf(v.z - bf2f(h.z));
    h.w = f2bf(v.w); l.w = f2bf(v.w - bf2f(h.w));
    ((ushort4*)hi)[i] = h;
    ((ushort4*)lo)[i] = l;
}

// fused q pre-pass: read q once per 32x32 tile -> write q_hi, q_lo (straight)
// and qT_hi (transposed).
__global__ void fuse_cvt_q(const float* __restrict__ q, u16* __restrict__ hi,
                           u16* __restrict__ lo, u16* __restrict__ thi)
{
    __shared__ float t[32][33];
    const long long z = blockIdx.z;
    const long long base = z * 1048576;
    const int r0 = blockIdx.y * 32, c0 = blockIdx.x * 32;
    for (int j = threadIdx.y; j < 32; j += 8) {
        const float v = q[base + (long long)(r0 + j) * 1024 + c0 + threadIdx.x];
        t[j][threadIdx.x] = v;
        const long long o = base + (long long)(r0 + j) * 1024 + c0 + threadIdx.x;
        const u16 h = f2bf(v);
        hi[o] = h;
        lo[o] = f2bf(v - bf2f(h));
    }
    __syncthreads();
    for (int j = threadIdx.y; j < 32; j += 8)
        thi[base + (long long)(c0 + j) * 1024 + r0 + threadIdx.x] = f2bf(t[threadIdx.x][j]);
}

// out[c][r] = in[r][c] with bf16 hi/lo conversion (W pre-pass)
__global__ void transpose_cvt_w(const float* __restrict__ in, u16* __restrict__ hi,
                                u16* __restrict__ lo)
{
    __shared__ float t[32][33];
    const int r0 = blockIdx.y * 32, c0 = blockIdx.x * 32;
    for (int j = threadIdx.y; j < 32; j += 8)
        t[j][threadIdx.x] = in[(long long)(r0 + j) * 1024 + c0 + threadIdx.x];
    __syncthreads();
    for (int j = threadIdx.y; j < 32; j += 8) {
        const float v = t[threadIdx.x][j];
        const long long o = (long long)(c0 + j) * 1024 + r0 + threadIdx.x;
        const u16 h = f2bf(v);
        hi[o] = h;
        lo[o] = f2bf(v - bf2f(h));
    }
}

// row softmax (fp32 in, bf16 out), one 256-thread block per 1024-elem row
__global__ void softmax_bf16(const float* __restrict__ S, u16* __restrict__ A)
{
    const long long row = blockIdx.x;
    const float* r = S + row * (long long)LQ_N;
    const int t = threadIdx.x;
    float4 v = ((const float4*)r)[t];

    float m = fmaxf(fmaxf(v.x, v.y), fmaxf(v.z, v.w));
#pragma unroll
    for (int off = 32; off > 0; off >>= 1)
        m = fmaxf(m, __shfl_xor(m, off));

    __shared__ float red[4];
    const int lane = t & 63, wid = t >> 6;
    if (lane == 0) red[wid] = m;
    __syncthreads();
    m = fmaxf(fmaxf(red[0], red[1]), fmaxf(red[2], red[3]));
    __syncthreads();

    v.x = __expf(v.x - m); v.y = __expf(v.y - m);
    v.z = __expf(v.z - m); v.w = __expf(v.w - m);
    float s = v.x + v.y + v.z + v.w;
#pragma unroll
    for (int off = 32; off > 0; off >>= 1)
        s += __shfl_xor(s, off);
    if (lane == 0) red[wid] = s;
    __syncthreads();
    s = red[0] + red[1] + red[2] + red[3];

    const float inv = 1.0f / s;
    ushort4 o;
    o.x = f2bf(v.x * inv); o.y = f2bf(v.y * inv);
    o.z = f2bf(v.z * inv); o.w = f2bf(v.w * inv);
    ((ushort4*)(A + row * (long long)LQ_N))[t] = o;
}

// ---------------------------------------------------------------------------
// Fallback fp32 path (round-1, verified; needs only 128 MB ws)
// ---------------------------------------------------------------------------
#define BM 128
#define BN 128
#define BK 8
#define TM 8
#define TN 8

template<bool TRANSB, bool BIAS, bool RELU>
__launch_bounds__(256)
__global__ void gemm_k(const float* __restrict__ A, const float* __restrict__ Bmat,
                       const float* __restrict__ bias, float* __restrict__ C,
                       int M, int N, int K,
                       long long sA, long long sB, long long sC)
{
    __shared__ float As[BK][BM];
    __shared__ float Bs[BK][BN];
    const int tid = threadIdx.x;
    const int tx = tid & 15;
    const int ty = tid >> 4;
    const int bn = blockIdx.x * BN;
    const int bm = blockIdx.y * BM;
    const long long z = blockIdx.z;
    A += z * sA; Bmat += z * sB; C += z * sC;
    float acc[TM][TN];
#pragma unroll
    for (int i = 0; i < TM; i++)
#pragma unroll
        for (int j = 0; j < TN; j++) acc[i][j] = 0.f;
    const int arow = tid >> 1;
    const int acol = (tid & 1) * 4;
    const int bk_n = tid >> 5;
    const int bn_n = (tid & 31) * 4;
    for (int k0 = 0; k0 < K; k0 += BK) {
        float4 a4 = *(const float4*)&A[(long long)(bm + arow) * K + k0 + acol];
        As[acol + 0][arow] = a4.x; As[acol + 1][arow] = a4.y;
        As[acol + 2][arow] = a4.z; As[acol + 3][arow] = a4.w;
        if (TRANSB) {
            float4 b4 = *(const float4*)&Bmat[(long long)(bn + arow) * K + k0 + acol];
            Bs[acol + 0][arow] = b4.x; Bs[acol + 1][arow] = b4.y;
            Bs[acol + 2][arow] = b4.z; Bs[acol + 3][arow] = b4.w;
        } else {
            float4 b4 = *(const float4*)&Bmat[(long long)(k0 + bk_n) * N + bn + bn_n];
            *(float4*)&Bs[bk_n][bn_n] = b4;
        }
        __syncthreads();
#pragma unroll
        for (int k = 0; k < BK; k++) {
            float a[TM], b[TN];
            *(float4*)&a[0] = *(const float4*)&As[k][ty * TM];
            *(float4*)&a[4] = *(const float4*)&As[k][ty * TM + 4];
            *(float4*)&b[0] = *(const float4*)&Bs[k][tx * TN];
            *(float4*)&b[4] = *(const float4*)&Bs[k][tx * TN + 4];
#pragma unroll
            for (int i = 0; i < TM; i++)
#pragma unroll
                for (int j = 0; j < TN; j++)
                    acc[i][j] = fmaf(a[i], b[j], acc[i][j]);
        }
        __syncthreads();
    }
#pragma unroll
    for (int i = 0; i < TM; i++) {
        const int row = bm + ty * TM + i;
#pragma unroll
        for (int j = 0; j < TN; j += 4) {
            const int col = bn + tx * TN + j;
            float4 v;
            v.x = acc[i][j + 0]; v.y = acc[i][j + 1];
            v.z = acc[i][j + 2]; v.w = acc[i][j + 3];
            if (BIAS) {
                v.x += bias[col + 0]; v.y += bias[col + 1];
                v.z += bias[col + 2]; v.w += bias[col + 3];
            }
            if (RELU) {
                v.x = fmaxf(v.x, 0.f); v.y = fmaxf(v.y, 0.f);
                v.z = fmaxf(v.z, 0.f); v.w = fmaxf(v.w, 0.f);
            }
            *(float4*)&C[(long long)row * N + col] = v;
        }
    }
}

__global__ void softmax_k(float* __restrict__ S)
{
    const long long row = blockIdx.x;
    float* r = S + row * (long long)LQ_N;
    const int t = threadIdx.x;
    float4 v = ((float4*)r)[t];
    float m = fmaxf(fmaxf(v.x, v.y), fmaxf(v.z, v.w));
#pragma unroll
    for (int off = 32; off > 0; off >>= 1)
        m = fmaxf(m, __shfl_xor(m, off));
    __shared__ float red[4];
    const int lane = t & 63, wid = t >> 6;
    if (lane == 0) red[wid] = m;
    __syncthreads();
    m = fmaxf(fmaxf(red[0], red[1]), fmaxf(red[2], red[3]));
    __syncthreads();
    v.x = __expf(v.x - m); v.y = __expf(v.y - m);
    v.z = __expf(v.z - m); v.w = __expf(v.w - m);
    float s = v.x + v.y + v.z + v.w;
#pragma unroll
    for (int off = 32; off > 0; off >>= 1)
        s += __shfl_xor(s, off);
    if (lane == 0) red[wid] = s;
    __syncthreads();
    s = red[0] + red[1] + red[2] + red[3];
    const float inv = 1.0f / s;
    v.x *= inv; v.y *= inv; v.z *= inv; v.w *= inv;
    ((float4*)r)[t] = v;
}

extern "C" void kernel_launch(void* const* d_in, const int* in_sizes, int n_in,
                              void* d_out, int out_size, void* d_ws, size_t ws_size,
                              hipStream_t stream)
{
    const float* p    = (const float*)d_in[0];
    const float* q    = (const float*)d_in[1];
    const float* W    = (const float*)d_in[2];
    const float* bias = (const float*)d_in[3];
    float* out = (float*)d_out;

    const size_t MB32 = 33554432ull;                 // 16M bf16
    const size_t NEED = 7 * MB32 + 2 * 2097152ull;   // 228 MB + 4 MB

    if (ws_size >= NEED) {
        char* w = (char*)d_ws;
        u16* p_hi    = (u16*)(w + 0 * MB32);
        u16* p_lo    = (u16*)(w + 1 * MB32);
        u16* q_hi    = (u16*)(w + 2 * MB32);
        u16* q_lo    = (u16*)(w + 3 * MB32);
        u16* keys_hi = (u16*)(w + 4 * MB32);
        u16* keys_lo = (u16*)(w + 5 * MB32);
        u16* qT_hi   = (u16*)(w + 6 * MB32);
        u16* Wt_hi   = (u16*)(w + 7 * MB32);
        u16* Wt_lo   = (u16*)(w + 7 * MB32 + 2097152);
        float* scores = (float*)(w + 2 * MB32);  // reuses q_hi/q_lo after GEMM1
        u16* attn     = (u16*)(w + 0 * MB32);    // reuses p_hi after GEMM2

        const long long n4 = (long long)B_N * LQ_N * H_N / 4;
        split_cvt<<<dim3((unsigned)(n4 / 256)), 256, 0, stream>>>(p, p_hi, p_lo, n4);
        fuse_cvt_q<<<dim3(32, 32, B_N), dim3(32, 8), 0, stream>>>(q, q_hi, q_lo, qT_hi);
        transpose_cvt_w<<<dim3(32, 32, 1), dim3(32, 8), 0, stream>>>(W, Wt_hi, Wt_lo);

        // keys = q @ W + b : split 3-term. M=16384, N=1024: 128x8 = 1024 blocks.
        gemm3t<false, 1><<<1024, 256, 0, stream>>>(
            q_hi, q_lo, Wt_hi, Wt_lo, bias, nullptr, keys_hi, keys_lo,
            H_N, /*gn=*/8, /*gmn=*/1024, 0, 0, 0);

        // scores[b] = p[b] @ keys[b]^T : per batch 8x8 tiles, 16 batches.
        gemm3t<false, 0><<<1024, 256, 0, stream>>>(
            p_hi, p_lo, keys_hi, keys_lo, nullptr, scores, nullptr, nullptr,
            LQ_N, /*gn=*/8, /*gmn=*/64,
            (long long)LP_N * H_N, (long long)LQ_N * H_N, (long long)LP_N * LQ_N);

        softmax_bf16<<<B_N * LP_N, 256, 0, stream>>>(scores, attn);

        // out[b] = relu(attn[b] @ q[b]) : dense bf16 (A=attn, B=qT).
        gemm3t<true, 2><<<1024, 256, 0, stream>>>(
            attn, attn, qT_hi, qT_hi, nullptr, out, nullptr, nullptr,
            H_N, /*gn=*/8, /*gmn=*/64,
            (long long)LP_N * LQ_N, (long long)H_N * LQ_N, (long long)LP_N * H_N);
    } else {
        float* keys   = (float*)d_ws;
        float* scores = keys + (long long)B_N * LQ_N * H_N;

        gemm_k<false, true, false><<<dim3(H_N / BN, (B_N * LQ_N) / BM, 1), 256, 0, stream>>>(
            q, W, bias, keys, B_N * LQ_N, H_N, H_N, 0, 0, 0);
        gemm_k<true, false, false><<<dim3(LQ_N / BN, LP_N / BM, B_N), 256, 0, stream>>>(
            p, keys, nullptr, scores, LP_N, LQ_N, H_N,
            (long long)LP_N * H_N, (long long)LQ_N * H_N, (long long)LP_N * LQ_N);
        softmax_k<<<B_N * LP_N, 256, 0, stream>>>(scores);
        gemm_k<false, false, true><<<dim3(H_N / BN, LP_N / BM, B_N), 256, 0, stream>>>(
            scores, q, nullptr, out, LP_N, H_N, LQ_N,
            (long long)LP_N * LQ_N, (long long)LQ_N * H_N, (long long)LP_N * H_N);
    }
}

// Round 12
// 255.039 us; speedup vs baseline: 1.3041x; 1.3041x over previous
//
#include <hip/hip_runtime.h>
#include <hip/hip_bf16.h>

#define B_N 16
#define LP_N 1024
#define LQ_N 1024
#define H_N 1024

typedef unsigned short u16;
typedef __attribute__((ext_vector_type(8))) _Float16 f16x8;
typedef __attribute__((ext_vector_type(4))) float f32x4;

__device__ __forceinline__ u16 f2h(float x) {
    _Float16 h = (_Float16)x;
    return *(u16*)&h;
}
__device__ __forceinline__ float h2f(u16 u) {
    _Float16 h;
    *(u16*)&h = u;
    return (float)h;
}

__device__ __forceinline__ void load_lds16(const u16* g, u16* l) {
    __builtin_amdgcn_global_load_lds(
        (const __attribute__((address_space(1))) void*)g,
        (__attribute__((address_space(3))) void*)l, 16, 0, 0);
}

#define MFMA_F16(a, b, c) __builtin_amdgcn_mfma_f32_16x16x32_f16(a, b, c, 0, 0, 0)
#define VMW0()  asm volatile("s_waitcnt vmcnt(0)" ::: "memory")
#define LGKM8() asm volatile("s_waitcnt lgkmcnt(8)" ::: "memory")
#define LGKM0() asm volatile("s_waitcnt lgkmcnt(0)" ::: "memory")
#define SCHB()  __builtin_amdgcn_sched_barrier(0)
#define SBAR()  __builtin_amdgcn_s_barrier()

// ---------------------------------------------------------------------------
// 256x256 fp16-split MFMA GEMM, NT form (R12).
// R3-R11 showed the split GEMMs pinned at ~991 TF effective = the 2-barrier
// structure ceiling; so reduce WORK via numerics: fp16 (11 mantissa bits)
// instead of bf16 (8). Keys/scores error budget: keys errors amplify
// sqrt(K)=32x into logits (std 32), needing <=2^-12 relative -> fp16-SINGLE
// B operand suffices (bf16-single would not). Scheme:
//   GEMM1: keys = (q_hi + q_lo) @ W_f16      -> 2 MFMA terms
//   GEMM2: scores = (p_hi + p_lo) @ keys_f16 -> 2 terms
//   GEMM3: out = relu(attn_f16 @ q_f16)      -> 1 term (fp16 also SHRINKS
//          the previously-dominant bf16 rounding error ~8x)
// Total MFMA work 5 units vs R9's 7.
// Structure = R9 verified: BK=32, 8 waves (2Mx4N), per-wave 128x64;
// regions {A_hi, A_lo, B} each staged once (48KB/buf split, dbuf 96KB);
// one vmcnt(0)+s_barrier per tile; t+1 staged right after front reads;
// all 20 ds_reads issued up front, lgkmcnt(8) before T1 (al-latency hides
// under T1's 32 MFMA), lgkmcnt(0) before T2 (rule #18 sched_barrier after).
// Swizzle (verified 0-conflict): 16B slot s_phys = s_log ^ ((row>>1)&3) on
// pre-swizzled global source AND frag ds_read offsets (rule #21).
// SPLIT=false: 2 regions {A, B}, T1 only. EPI: 0=fp32, 1=+bias fp16, 2=relu.
// ---------------------------------------------------------------------------
template<bool SPLIT, int EPI>
__launch_bounds__(512, 2)
__global__ void gemm2t(const u16* __restrict__ Ahi, const u16* __restrict__ Alo,
                       const u16* __restrict__ Bm,
                       const float* __restrict__ bias,
                       float* __restrict__ Cf, u16* __restrict__ Ch,
                       int N, int gn, int gmn,
                       long long sA, long long sB, long long sC)
{
    constexpr int REG  = 8192;                   // u16 per 256x32 region (16KB)
    constexpr int O_AL = REG;                    // split only
    constexpr int O_B  = SPLIT ? 2 * REG : REG;
    constexpr int BUF  = SPLIT ? 3 * REG : 2 * REG;
    __shared__ __align__(16) u16 lds[2 * BUF];   // 96KB split / 64KB dense

    const int tid  = threadIdx.x;
    const int lane = tid & 63;
    const int wv   = tid >> 6;
    const int wr   = wv >> 2, wc = wv & 3;       // 2M x 4N waves

    // XCD-contiguous block swizzle (nwg=256 -> 32 contiguous tiles/XCD)
    const int d   = blockIdx.x;
    const int cpx = gridDim.x >> 3;
    const int swz = (d & 7) * cpx + (d >> 3);
    const long long z = swz / gmn;
    const int r_  = swz % gmn;
    const int bm  = (r_ / gn) * 256;
    const int bn  = (r_ % gn) * 256;

    const char* pAh = (const char*)(Ahi + z * sA);
    const char* pAl = (const char*)(Alo + z * sA);
    const char* pB  = (const char*)(Bm + z * sB);

    // ---- staging (R9-verified): region = 1024 x 16B chunks. chunk c:
    // row=c>>2, phys slot=c&3, src logical slot=(c&3)^((row>>1)&3).
    // thread t stages chunks {t, t+512} (rows r0, r0+128; same XOR).
    const int r0 = tid >> 2;                     // 0..127
    const int xc = (tid & 3) ^ ((r0 >> 1) & 3);
    const long long aof = (long long)(bm + r0) * 2048 + xc * 16;
    const long long bof = (long long)(bn + r0) * 2048 + xc * 16;
    const long long ao2 = aof + 128 * 2048;
    const long long bo2 = bof + 128 * 2048;
    const int d0 = tid * 8;                      // u16 dest offset (chunk t)
    const int d1 = d0 + 4096;                    // chunk t+512

    // ---- fragment ds_read offsets (u16 units within region), same swizzle
    int offA[8], offB[4];
#pragma unroll
    for (int i = 0; i < 8; ++i) {
        const int r = wr * 128 + i * 16 + (lane & 15);
        offA[i] = r * 32 + ((((lane >> 4) ^ (r >> 1)) & 3) << 3);
    }
#pragma unroll
    for (int j = 0; j < 4; ++j) {
        const int r = wc * 64 + j * 16 + (lane & 15);
        offB[j] = r * 32 + ((((lane >> 4) ^ (r >> 1)) & 3) << 3);
    }

    f32x4 acc[8][4];
#pragma unroll
    for (int i = 0; i < 8; ++i)
#pragma unroll
        for (int j = 0; j < 4; ++j)
            acc[i][j] = (f32x4){0.f, 0.f, 0.f, 0.f};

#define STG(NB, KB) do {                                                      \
        load_lds16((const u16*)(pAh + aof + (KB)), lds + (NB) + d0);          \
        load_lds16((const u16*)(pAh + ao2 + (KB)), lds + (NB) + d1);          \
        load_lds16((const u16*)(pB + bof + (KB)), lds + (NB) + O_B + d0);     \
        load_lds16((const u16*)(pB + bo2 + (KB)), lds + (NB) + O_B + d1);     \
        if constexpr (SPLIT) {                                                \
            load_lds16((const u16*)(pAl + aof + (KB)), lds + (NB) + O_AL + d0); \
            load_lds16((const u16*)(pAl + ao2 + (KB)), lds + (NB) + O_AL + d1); \
        }                                                                     \
    } while (0)

#define TERM(AF, BF) do {                                                     \
        __builtin_amdgcn_s_setprio(1);                                        \
        _Pragma("unroll")                                                     \
        for (int i = 0; i < 8; ++i)                                           \
            _Pragma("unroll")                                                 \
            for (int j = 0; j < 4; ++j)                                       \
                acc[i][j] = MFMA_F16(AF[i], BF[j], acc[i][j]);                \
        __builtin_amdgcn_s_setprio(0);                                        \
    } while (0)

    constexpr int NT = 32;                       // K=1024 / BK=32

    STG(0, 0);                                   // prologue: tile 0 -> buf 0

    for (int t = 0; t < NT; ++t) {
        const int cb = (t & 1) ? BUF : 0;
        const int nb = (t & 1) ? 0 : BUF;
        const long long kb = (long long)(t + 1) * 64;  // bytes

        VMW0();                  // tile t staged loads retired (per wave)
        SBAR();                  // cross-wave publish
        f16x8 b[4], ah[8], al[8];
#pragma unroll
        for (int j = 0; j < 4; ++j)
            b[j] = *(const f16x8*)(lds + cb + O_B + offB[j]);
#pragma unroll
        for (int i = 0; i < 8; ++i)
            ah[i] = *(const f16x8*)(lds + cb + offA[i]);
        if constexpr (SPLIT) {
#pragma unroll
            for (int i = 0; i < 8; ++i)
                al[i] = *(const f16x8*)(lds + cb + O_AL + offA[i]);
        }
        if (t + 1 < NT) STG(nb, kb);             // issue t+1 early (max slack)
        if constexpr (SPLIT) { LGKM8(); } else { LGKM0(); }
        SCHB();
        TERM(ah, b);                             // T1: 32 MFMA (al in flight)
        if constexpr (SPLIT) {
            LGKM0(); SCHB();
            TERM(al, b);                         // T2
        }
    }
#undef STG
#undef TERM

    // epilogue; C/D map: col = lane&15, row = (lane>>4)*4 + e  [m89/m91]
    const long long Cbase = z * sC;
#pragma unroll
    for (int i = 0; i < 8; ++i) {
        const int row0 = bm + wr * 128 + i * 16 + ((lane >> 4) << 2);
#pragma unroll
        for (int j = 0; j < 4; ++j) {
            const int col = bn + wc * 64 + j * 16 + (lane & 15);
#pragma unroll
            for (int e = 0; e < 4; ++e) {
                const float v = acc[i][j][e];
                const long long idx = Cbase + (long long)(row0 + e) * N + col;
                if constexpr (EPI == 0) {
                    Cf[idx] = v;
                } else if constexpr (EPI == 1) {
                    Ch[idx] = f2h(v + bias[col]);
                } else {
                    Cf[idx] = fmaxf(v, 0.f);
                }
            }
        }
    }
}

// fp32 -> fp16 hi/lo split, 4 elems/thread
__global__ void split_cvt(const float* __restrict__ in, u16* __restrict__ hi,
                          u16* __restrict__ lo, long long n4)
{
    const long long i = (long long)blockIdx.x * 256 + threadIdx.x;
    if (i >= n4) return;
    const float4 v = ((const float4*)in)[i];
    ushort4 h, l;
    h.x = f2h(v.x); l.x = f2h(v.x - h2f(h.x));
    h.y = f2h(v.y); l.y = f2h(v.y - h2f(h.y));
    h.z = f2h(v.z); l.z = f2h(v.z - h2f(h.z));
    h.w = f2h(v.w); l.w = f2h(v.w - h2f(h.w));
    ((ushort4*)hi)[i] = h;
    ((ushort4*)lo)[i] = l;
}

// fused q pre-pass: read q once per 32x32 tile -> q_hi, q_lo (straight, fp16)
// and qT (transposed, fp16 single for GEMM3's B).
__global__ void fuse_cvt_q(const float* __restrict__ q, u16* __restrict__ hi,
                           u16* __restrict__ lo, u16* __restrict__ thi)
{
    __shared__ float t[32][33];
    const long long z = blockIdx.z;
    const long long base = z * 1048576;
    const int r0 = blockIdx.y * 32, c0 = blockIdx.x * 32;
    for (int j = threadIdx.y; j < 32; j += 8) {
        const float v = q[base + (long long)(r0 + j) * 1024 + c0 + threadIdx.x];
        t[j][threadIdx.x] = v;
        const long long o = base + (long long)(r0 + j) * 1024 + c0 + threadIdx.x;
        const u16 h = f2h(v);
        hi[o] = h;
        lo[o] = f2h(v - h2f(h));
    }
    __syncthreads();
    for (int j = threadIdx.y; j < 32; j += 8)
        thi[base + (long long)(c0 + j) * 1024 + r0 + threadIdx.x] = f2h(t[threadIdx.x][j]);
}

// Wt[c][r] = W[r][c], fp16 single (W pre-pass; W rounding error negligible)
__global__ void transpose_cvt_w(const float* __restrict__ in, u16* __restrict__ hi)
{
    __shared__ float t[32][33];
    const int r0 = blockIdx.y * 32, c0 = blockIdx.x * 32;
    for (int j = threadIdx.y; j < 32; j += 8)
        t[j][threadIdx.x] = in[(long long)(r0 + j) * 1024 + c0 + threadIdx.x];
    __syncthreads();
    for (int j = threadIdx.y; j < 32; j += 8)
        hi[(long long)(c0 + j) * 1024 + r0 + threadIdx.x] = f2h(t[threadIdx.x][j]);
}

// row softmax (fp32 in, fp16 out), one 256-thread block per 1024-elem row
__global__ void softmax_f16(const float* __restrict__ S, u16* __restrict__ A)
{
    const long long row = blockIdx.x;
    const float* r = S + row * (long long)LQ_N;
    const int t = threadIdx.x;
    float4 v = ((const float4*)r)[t];

    float m = fmaxf(fmaxf(v.x, v.y), fmaxf(v.z, v.w));
#pragma unroll
    for (int off = 32; off > 0; off >>= 1)
        m = fmaxf(m, __shfl_xor(m, off));

    __shared__ float red[4];
    const int lane = t & 63, wid = t >> 6;
    if (lane == 0) red[wid] = m;
    __syncthreads();
    m = fmaxf(fmaxf(red[0], red[1]), fmaxf(red[2], red[3]));
    __syncthreads();

    v.x = __expf(v.x - m); v.y = __expf(v.y - m);
    v.z = __expf(v.z - m); v.w = __expf(v.w - m);
    float s = v.x + v.y + v.z + v.w;
#pragma unroll
    for (int off = 32; off > 0; off >>= 1)
        s += __shfl_xor(s, off);
    if (lane == 0) red[wid] = s;
    __syncthreads();
    s = red[0] + red[1] + red[2] + red[3];

    const float inv = 1.0f / s;
    ushort4 o;
    o.x = f2h(v.x * inv); o.y = f2h(v.y * inv);
    o.z = f2h(v.z * inv); o.w = f2h(v.w * inv);
    ((ushort4*)(A + row * (long long)LQ_N))[t] = o;
}

// ---------------------------------------------------------------------------
// Fallback fp32 path (round-1, verified; needs only 128 MB ws)
// ---------------------------------------------------------------------------
#define BM 128
#define BN 128
#define BK 8
#define TM 8
#define TN 8

template<bool TRANSB, bool BIAS, bool RELU>
__launch_bounds__(256)
__global__ void gemm_k(const float* __restrict__ A, const float* __restrict__ Bmat,
                       const float* __restrict__ bias, float* __restrict__ C,
                       int M, int N, int K,
                       long long sA, long long sB, long long sC)
{
    __shared__ float As[BK][BM];
    __shared__ float Bs[BK][BN];
    const int tid = threadIdx.x;
    const int tx = tid & 15;
    const int ty = tid >> 4;
    const int bn = blockIdx.x * BN;
    const int bm = blockIdx.y * BM;
    const long long z = blockIdx.z;
    A += z * sA; Bmat += z * sB; C += z * sC;
    float acc[TM][TN];
#pragma unroll
    for (int i = 0; i < TM; i++)
#pragma unroll
        for (int j = 0; j < TN; j++) acc[i][j] = 0.f;
    const int arow = tid >> 1;
    const int acol = (tid & 1) * 4;
    const int bk_n = tid >> 5;
    const int bn_n = (tid & 31) * 4;
    for (int k0 = 0; k0 < K; k0 += BK) {
        float4 a4 = *(const float4*)&A[(long long)(bm + arow) * K + k0 + acol];
        As[acol + 0][arow] = a4.x; As[acol + 1][arow] = a4.y;
        As[acol + 2][arow] = a4.z; As[acol + 3][arow] = a4.w;
        if (TRANSB) {
            float4 b4 = *(const float4*)&Bmat[(long long)(bn + arow) * K + k0 + acol];
            Bs[acol + 0][arow] = b4.x; Bs[acol + 1][arow] = b4.y;
            Bs[acol + 2][arow] = b4.z; Bs[acol + 3][arow] = b4.w;
        } else {
            float4 b4 = *(const float4*)&Bmat[(long long)(k0 + bk_n) * N + bn + bn_n];
            *(float4*)&Bs[bk_n][bn_n] = b4;
        }
        __syncthreads();
#pragma unroll
        for (int k = 0; k < BK; k++) {
            float a[TM], b[TN];
            *(float4*)&a[0] = *(const float4*)&As[k][ty * TM];
            *(float4*)&a[4] = *(const float4*)&As[k][ty * TM + 4];
            *(float4*)&b[0] = *(const float4*)&Bs[k][tx * TN];
            *(float4*)&b[4] = *(const float4*)&Bs[k][tx * TN + 4];
#pragma unroll
            for (int i = 0; i < TM; i++)
#pragma unroll
                for (int j = 0; j < TN; j++)
                    acc[i][j] = fmaf(a[i], b[j], acc[i][j]);
        }
        __syncthreads();
    }
#pragma unroll
    for (int i = 0; i < TM; i++) {
        const int row = bm + ty * TM + i;
#pragma unroll
        for (int j = 0; j < TN; j += 4) {
            const int col = bn + tx * TN + j;
            float4 v;
            v.x = acc[i][j + 0]; v.y = acc[i][j + 1];
            v.z = acc[i][j + 2]; v.w = acc[i][j + 3];
            if (BIAS) {
                v.x += bias[col + 0]; v.y += bias[col + 1];
                v.z += bias[col + 2]; v.w += bias[col + 3];
            }
            if (RELU) {
                v.x = fmaxf(v.x, 0.f); v.y = fmaxf(v.y, 0.f);
                v.z = fmaxf(v.z, 0.f); v.w = fmaxf(v.w, 0.f);
            }
            *(float4*)&C[(long long)row * N + col] = v;
        }
    }
}

__global__ void softmax_k(float* __restrict__ S)
{
    const long long row = blockIdx.x;
    float* r = S + row * (long long)LQ_N;
    const int t = threadIdx.x;
    float4 v = ((float4*)r)[t];
    float m = fmaxf(fmaxf(v.x, v.y), fmaxf(v.z, v.w));
#pragma unroll
    for (int off = 32; off > 0; off >>= 1)
        m = fmaxf(m, __shfl_xor(m, off));
    __shared__ float red[4];
    const int lane = t & 63, wid = t >> 6;
    if (lane == 0) red[wid] = m;
    __syncthreads();
    m = fmaxf(fmaxf(red[0], red[1]), fmaxf(red[2], red[3]));
    __syncthreads();
    v.x = __expf(v.x - m); v.y = __expf(v.y - m);
    v.z = __expf(v.z - m); v.w = __expf(v.w - m);
    float s = v.x + v.y + v.z + v.w;
#pragma unroll
    for (int off = 32; off > 0; off >>= 1)
        s += __shfl_xor(s, off);
    if (lane == 0) red[wid] = s;
    __syncthreads();
    s = red[0] + red[1] + red[2] + red[3];
    const float inv = 1.0f / s;
    v.x *= inv; v.y *= inv; v.z *= inv; v.w *= inv;
    ((float4*)r)[t] = v;
}

extern "C" void kernel_launch(void* const* d_in, const int* in_sizes, int n_in,
                              void* d_out, int out_size, void* d_ws, size_t ws_size,
                              hipStream_t stream)
{
    const float* p    = (const float*)d_in[0];
    const float* q    = (const float*)d_in[1];
    const float* W    = (const float*)d_in[2];
    const float* bias = (const float*)d_in[3];
    float* out = (float*)d_out;

    const size_t MB32 = 33554432ull;                 // 16M fp16
    const size_t NEED = 6 * MB32 + 2097152ull;       // 192 MB + 2 MB

    if (ws_size >= NEED) {
        char* w = (char*)d_ws;
        u16* p_hi  = (u16*)(w + 0 * MB32);
        u16* p_lo  = (u16*)(w + 1 * MB32);
        u16* q_hi  = (u16*)(w + 2 * MB32);
        u16* q_lo  = (u16*)(w + 3 * MB32);
        u16* keys  = (u16*)(w + 4 * MB32);
        u16* qT    = (u16*)(w + 5 * MB32);
        u16* Wt    = (u16*)(w + 6 * MB32);
        float* scores = (float*)(w + 2 * MB32);  // reuses q_hi/q_lo after GEMM1
        u16* attn     = (u16*)(w + 0 * MB32);    // reuses p_hi after GEMM2

        const long long n4 = (long long)B_N * LQ_N * H_N / 4;
        split_cvt<<<dim3((unsigned)(n4 / 256)), 256, 0, stream>>>(p, p_hi, p_lo, n4);
        fuse_cvt_q<<<dim3(32, 32, B_N), dim3(32, 8), 0, stream>>>(q, q_hi, q_lo, qT);
        transpose_cvt_w<<<dim3(32, 32, 1), dim3(32, 8), 0, stream>>>(W, Wt);

        // keys = (q_hi + q_lo) @ Wt + b : 2 terms, fp16-single keys out.
        gemm2t<true, 1><<<256, 512, 0, stream>>>(
            q_hi, q_lo, Wt, bias, nullptr, keys,
            H_N, /*gn=*/4, /*gmn=*/256, 0, 0, 0);

        // scores[b] = (p_hi + p_lo)[b] @ keys[b]^T : 2 terms, fp32 out.
        gemm2t<true, 0><<<256, 512, 0, stream>>>(
            p_hi, p_lo, keys, nullptr, scores, nullptr,
            LQ_N, /*gn=*/4, /*gmn=*/16,
            (long long)LP_N * H_N, (long long)LQ_N * H_N, (long long)LP_N * LQ_N);

        softmax_f16<<<B_N * LP_N, 256, 0, stream>>>(scores, attn);

        // out[b] = relu(attn[b] @ q[b]) : dense fp16.
        gemm2t<false, 2><<<256, 512, 0, stream>>>(
            attn, attn, qT, nullptr, out, nullptr,
            H_N, /*gn=*/4, /*gmn=*/16,
            (long long)LP_N * LQ_N, (long long)H_N * LQ_N, (long long)LP_N * H_N);
    } else {
        float* keys   = (float*)d_ws;
        float* scores = keys + (long long)B_N * LQ_N * H_N;

        gemm_k<false, true, false><<<dim3(H_N / BN, (B_N * LQ_N) / BM, 1), 256, 0, stream>>>(
            q, W, bias, keys, B_N * LQ_N, H_N, H_N, 0, 0, 0);
        gemm_k<true, false, false><<<dim3(LQ_N / BN, LP_N / BM, B_N), 256, 0, stream>>>(
            p, keys, nullptr, scores, LP_N, LQ_N, H_N,
            (long long)LP_N * H_N, (long long)LQ_N * H_N, (long long)LP_N * LQ_N);
        softmax_k<<<B_N * LP_N, 256, 0, stream>>>(scores);
        gemm_k<false, false, true><<<dim3(H_N / BN, LP_N / BM, B_N), 256, 0, stream>>>(
            scores, q, nullptr, out, LP_N, H_N, LQ_N,
            (long long)LP_N * LQ_N, (long long)LQ_N * H_N, (long long)LP_N * H_N);
    }
}

// Round 13
// 231.534 us; speedup vs baseline: 1.4365x; 1.1015x over previous
//
#include <hip/hip_runtime.h>
#include <hip/hip_bf16.h>

#define B_N 16
#define LP_N 1024
#define LQ_N 1024
#define H_N 1024

typedef unsigned short u16;
typedef __attribute__((ext_vector_type(8))) _Float16 f16x8;
typedef __attribute__((ext_vector_type(4))) float f32x4;

__device__ __forceinline__ u16 f2h(float x) {
    _Float16 h = (_Float16)x;
    return *(u16*)&h;
}
__device__ __forceinline__ float h2f(u16 u) {
    _Float16 h;
    *(u16*)&h = u;
    return (float)h;
}

__device__ __forceinline__ void load_lds16(const u16* g, u16* l) {
    __builtin_amdgcn_global_load_lds(
        (const __attribute__((address_space(1))) void*)g,
        (__attribute__((address_space(3))) void*)l, 16, 0, 0);
}

#define MFMA_F16(a, b, c) __builtin_amdgcn_mfma_f32_16x16x32_f16(a, b, c, 0, 0, 0)
#define VMW0()  asm volatile("s_waitcnt vmcnt(0)" ::: "memory")
#define LGKM8() asm volatile("s_waitcnt lgkmcnt(8)" ::: "memory")
#define LGKM0() asm volatile("s_waitcnt lgkmcnt(0)" ::: "memory")
#define SCHB()  __builtin_amdgcn_sched_barrier(0)
#define SBAR()  __builtin_amdgcn_s_barrier()

// ---------------------------------------------------------------------------
// 256x256 fp16 MFMA GEMM, NT form (R12 kernel, unchanged in R13).
// R13 numerics: GEMM2 drops the p-split (p fp16-single) -> 1 term. Error
// budget: p-rounding adds sqrt(K)*2^-12 ~ 0.0078 std to logits, same size
// as the keys-storage term already present in R12's measured 0.0488 absmax
// -> predicted ~0.06-0.07 < 0.104 threshold. GEMM1 keeps the q-split.
//   GEMM1: keys = (q_hi + q_lo) @ W_f16      -> 2 MFMA terms
//   GEMM2: scores = p_f16 @ keys_f16^T       -> 1 term (dense)
//   GEMM3: out = relu(attn_f16 @ q_f16)      -> 1 term (dense)
// Structure (R9-verified): BK=32, 8 waves (2Mx4N), per-wave 128x64;
// regions {A_hi[,A_lo],B} staged once/tile; one vmcnt(0)+s_barrier per
// tile; t+1 staged right after front reads; lgkmcnt(8) before T1 hides
// al reads under T1's MFMA (rule #18 sched_barrier after each wait).
// Swizzle (verified 0-conflict): 16B slot s_phys = s_log ^ ((row>>1)&3) on
// pre-swizzled global source AND frag ds_read offsets (rule #21).
// SPLIT=false: 2 regions {A, B}, T1 only. EPI: 0=fp32, 1=+bias fp16, 2=relu.
// ---------------------------------------------------------------------------
template<bool SPLIT, int EPI>
__launch_bounds__(512, 2)
__global__ void gemm2t(const u16* __restrict__ Ahi, const u16* __restrict__ Alo,
                       const u16* __restrict__ Bm,
                       const float* __restrict__ bias,
                       float* __restrict__ Cf, u16* __restrict__ Ch,
                       int N, int gn, int gmn,
                       long long sA, long long sB, long long sC)
{
    constexpr int REG  = 8192;                   // u16 per 256x32 region (16KB)
    constexpr int O_AL = REG;                    // split only
    constexpr int O_B  = SPLIT ? 2 * REG : REG;
    constexpr int BUF  = SPLIT ? 3 * REG : 2 * REG;
    __shared__ __align__(16) u16 lds[2 * BUF];   // 96KB split / 64KB dense

    const int tid  = threadIdx.x;
    const int lane = tid & 63;
    const int wv   = tid >> 6;
    const int wr   = wv >> 2, wc = wv & 3;       // 2M x 4N waves

    // XCD-contiguous block swizzle (nwg=256 -> 32 contiguous tiles/XCD)
    const int d   = blockIdx.x;
    const int cpx = gridDim.x >> 3;
    const int swz = (d & 7) * cpx + (d >> 3);
    const long long z = swz / gmn;
    const int r_  = swz % gmn;
    const int bm  = (r_ / gn) * 256;
    const int bn  = (r_ % gn) * 256;

    const char* pAh = (const char*)(Ahi + z * sA);
    const char* pAl = (const char*)(Alo + z * sA);
    const char* pB  = (const char*)(Bm + z * sB);

    // ---- staging: region = 1024 x 16B chunks. chunk c: row=c>>2, phys
    // slot=c&3, src logical slot=(c&3)^((row>>1)&3). thread t stages chunks
    // {t, t+512} (rows r0, r0+128; same XOR). Row stride = 2048B.
    const int r0 = tid >> 2;                     // 0..127
    const int xc = (tid & 3) ^ ((r0 >> 1) & 3);
    const long long aof = (long long)(bm + r0) * 2048 + xc * 16;
    const long long bof = (long long)(bn + r0) * 2048 + xc * 16;
    const long long ao2 = aof + 128 * 2048;
    const long long bo2 = bof + 128 * 2048;
    const int d0 = tid * 8;                      // u16 dest offset (chunk t)
    const int d1 = d0 + 4096;                    // chunk t+512

    // ---- fragment ds_read offsets (u16 units within region), same swizzle
    int offA[8], offB[4];
#pragma unroll
    for (int i = 0; i < 8; ++i) {
        const int r = wr * 128 + i * 16 + (lane & 15);
        offA[i] = r * 32 + ((((lane >> 4) ^ (r >> 1)) & 3) << 3);
    }
#pragma unroll
    for (int j = 0; j < 4; ++j) {
        const int r = wc * 64 + j * 16 + (lane & 15);
        offB[j] = r * 32 + ((((lane >> 4) ^ (r >> 1)) & 3) << 3);
    }

    f32x4 acc[8][4];
#pragma unroll
    for (int i = 0; i < 8; ++i)
#pragma unroll
        for (int j = 0; j < 4; ++j)
            acc[i][j] = (f32x4){0.f, 0.f, 0.f, 0.f};

#define STG(NB, KB) do {                                                      \
        load_lds16((const u16*)(pAh + aof + (KB)), lds + (NB) + d0);          \
        load_lds16((const u16*)(pAh + ao2 + (KB)), lds + (NB) + d1);          \
        load_lds16((const u16*)(pB + bof + (KB)), lds + (NB) + O_B + d0);     \
        load_lds16((const u16*)(pB + bo2 + (KB)), lds + (NB) + O_B + d1);     \
        if constexpr (SPLIT) {                                                \
            load_lds16((const u16*)(pAl + aof + (KB)), lds + (NB) + O_AL + d0); \
            load_lds16((const u16*)(pAl + ao2 + (KB)), lds + (NB) + O_AL + d1); \
        }                                                                     \
    } while (0)

#define TERM(AF, BF) do {                                                     \
        __builtin_amdgcn_s_setprio(1);                                        \
        _Pragma("unroll")                                                     \
        for (int i = 0; i < 8; ++i)                                           \
            _Pragma("unroll")                                                 \
            for (int j = 0; j < 4; ++j)                                       \
                acc[i][j] = MFMA_F16(AF[i], BF[j], acc[i][j]);                \
        __builtin_amdgcn_s_setprio(0);                                        \
    } while (0)

    constexpr int NT = 32;                       // K=1024 / BK=32

    STG(0, 0);                                   // prologue: tile 0 -> buf 0

    for (int t = 0; t < NT; ++t) {
        const int cb = (t & 1) ? BUF : 0;
        const int nb = (t & 1) ? 0 : BUF;
        const long long kb = (long long)(t + 1) * 64;  // bytes

        VMW0();                  // tile t staged loads retired (per wave)
        SBAR();                  // cross-wave publish
        f16x8 b[4], ah[8], al[8];
#pragma unroll
        for (int j = 0; j < 4; ++j)
            b[j] = *(const f16x8*)(lds + cb + O_B + offB[j]);
#pragma unroll
        for (int i = 0; i < 8; ++i)
            ah[i] = *(const f16x8*)(lds + cb + offA[i]);
        if constexpr (SPLIT) {
#pragma unroll
            for (int i = 0; i < 8; ++i)
                al[i] = *(const f16x8*)(lds + cb + O_AL + offA[i]);
        }
        if (t + 1 < NT) STG(nb, kb);             // issue t+1 early (max slack)
        if constexpr (SPLIT) { LGKM8(); } else { LGKM0(); }
        SCHB();
        TERM(ah, b);                             // T1: 32 MFMA (al in flight)
        if constexpr (SPLIT) {
            LGKM0(); SCHB();
            TERM(al, b);                         // T2
        }
    }
#undef STG
#undef TERM

    // epilogue; C/D map: col = lane&15, row = (lane>>4)*4 + e  [m89/m91]
    const long long Cbase = z * sC;
#pragma unroll
    for (int i = 0; i < 8; ++i) {
        const int row0 = bm + wr * 128 + i * 16 + ((lane >> 4) << 2);
#pragma unroll
        for (int j = 0; j < 4; ++j) {
            const int col = bn + wc * 64 + j * 16 + (lane & 15);
#pragma unroll
            for (int e = 0; e < 4; ++e) {
                const float v = acc[i][j][e];
                const long long idx = Cbase + (long long)(row0 + e) * N + col;
                if constexpr (EPI == 0) {
                    Cf[idx] = v;
                } else if constexpr (EPI == 1) {
                    Ch[idx] = f2h(v + bias[col]);
                } else {
                    Cf[idx] = fmaxf(v, 0.f);
                }
            }
        }
    }
}

// fp32 -> fp16 single, 4 elems/thread (p pre-pass, R13: no lo needed)
__global__ void cvt_f16(const float* __restrict__ in, u16* __restrict__ o16,
                        long long n4)
{
    const long long i = (long long)blockIdx.x * 256 + threadIdx.x;
    if (i >= n4) return;
    const float4 v = ((const float4*)in)[i];
    ushort4 h;
    h.x = f2h(v.x); h.y = f2h(v.y); h.z = f2h(v.z); h.w = f2h(v.w);
    ((ushort4*)o16)[i] = h;
}

// fused q pre-pass: read q once per 32x32 tile -> q_hi, q_lo (straight, fp16)
// and qT (transposed, fp16 single for GEMM3's B).
__global__ void fuse_cvt_q(const float* __restrict__ q, u16* __restrict__ hi,
                           u16* __restrict__ lo, u16* __restrict__ thi)
{
    __shared__ float t[32][33];
    const long long z = blockIdx.z;
    const long long base = z * 1048576;
    const int r0 = blockIdx.y * 32, c0 = blockIdx.x * 32;
    for (int j = threadIdx.y; j < 32; j += 8) {
        const float v = q[base + (long long)(r0 + j) * 1024 + c0 + threadIdx.x];
        t[j][threadIdx.x] = v;
        const long long o = base + (long long)(r0 + j) * 1024 + c0 + threadIdx.x;
        const u16 h = f2h(v);
        hi[o] = h;
        lo[o] = f2h(v - h2f(h));
    }
    __syncthreads();
    for (int j = threadIdx.y; j < 32; j += 8)
        thi[base + (long long)(c0 + j) * 1024 + r0 + threadIdx.x] = f2h(t[threadIdx.x][j]);
}

// Wt[c][r] = W[r][c], fp16 single (W pre-pass; W rounding error negligible)
__global__ void transpose_cvt_w(const float* __restrict__ in, u16* __restrict__ hi)
{
    __shared__ float t[32][33];
    const int r0 = blockIdx.y * 32, c0 = blockIdx.x * 32;
    for (int j = threadIdx.y; j < 32; j += 8)
        t[j][threadIdx.x] = in[(long long)(r0 + j) * 1024 + c0 + threadIdx.x];
    __syncthreads();
    for (int j = threadIdx.y; j < 32; j += 8)
        hi[(long long)(c0 + j) * 1024 + r0 + threadIdx.x] = f2h(t[threadIdx.x][j]);
}

// row softmax (fp32 in, fp16 out), one 256-thread block per 1024-elem row
__global__ void softmax_f16(const float* __restrict__ S, u16* __restrict__ A)
{
    const long long row = blockIdx.x;
    const float* r = S + row * (long long)LQ_N;
    const int t = threadIdx.x;
    float4 v = ((const float4*)r)[t];

    float m = fmaxf(fmaxf(v.x, v.y), fmaxf(v.z, v.w));
#pragma unroll
    for (int off = 32; off > 0; off >>= 1)
        m = fmaxf(m, __shfl_xor(m, off));

    __shared__ float red[4];
    const int lane = t & 63, wid = t >> 6;
    if (lane == 0) red[wid] = m;
    __syncthreads();
    m = fmaxf(fmaxf(red[0], red[1]), fmaxf(red[2], red[3]));
    __syncthreads();

    v.x = __expf(v.x - m); v.y = __expf(v.y - m);
    v.z = __expf(v.z - m); v.w = __expf(v.w - m);
    float s = v.x + v.y + v.z + v.w;
#pragma unroll
    for (int off = 32; off > 0; off >>= 1)
        s += __shfl_xor(s, off);
    if (lane == 0) red[wid] = s;
    __syncthreads();
    s = red[0] + red[1] + red[2] + red[3];

    const float inv = 1.0f / s;
    ushort4 o;
    o.x = f2h(v.x * inv); o.y = f2h(v.y * inv);
    o.z = f2h(v.z * inv); o.w = f2h(v.w * inv);
    ((ushort4*)(A + row * (long long)LQ_N))[t] = o;
}

// ---------------------------------------------------------------------------
// Fallback fp32 path (round-1, verified; needs only 128 MB ws)
// ---------------------------------------------------------------------------
#define BM 128
#define BN 128
#define BK 8
#define TM 8
#define TN 8

template<bool TRANSB, bool BIAS, bool RELU>
__launch_bounds__(256)
__global__ void gemm_k(const float* __restrict__ A, const float* __restrict__ Bmat,
                       const float* __restrict__ bias, float* __restrict__ C,
                       int M, int N, int K,
                       long long sA, long long sB, long long sC)
{
    __shared__ float As[BK][BM];
    __shared__ float Bs[BK][BN];
    const int tid = threadIdx.x;
    const int tx = tid & 15;
    const int ty = tid >> 4;
    const int bn = blockIdx.x * BN;
    const int bm = blockIdx.y * BM;
    const long long z = blockIdx.z;
    A += z * sA; Bmat += z * sB; C += z * sC;
    float acc[TM][TN];
#pragma unroll
    for (int i = 0; i < TM; i++)
#pragma unroll
        for (int j = 0; j < TN; j++) acc[i][j] = 0.f;
    const int arow = tid >> 1;
    const int acol = (tid & 1) * 4;
    const int bk_n = tid >> 5;
    const int bn_n = (tid & 31) * 4;
    for (int k0 = 0; k0 < K; k0 += BK) {
        float4 a4 = *(const float4*)&A[(long long)(bm + arow) * K + k0 + acol];
        As[acol + 0][arow] = a4.x; As[acol + 1][arow] = a4.y;
        As[acol + 2][arow] = a4.z; As[acol + 3][arow] = a4.w;
        if (TRANSB) {
            float4 b4 = *(const float4*)&Bmat[(long long)(bn + arow) * K + k0 + acol];
            Bs[acol + 0][arow] = b4.x; Bs[acol + 1][arow] = b4.y;
            Bs[acol + 2][arow] = b4.z; Bs[acol + 3][arow] = b4.w;
        } else {
            float4 b4 = *(const float4*)&Bmat[(long long)(k0 + bk_n) * N + bn + bn_n];
            *(float4*)&Bs[bk_n][bn_n] = b4;
        }
        __syncthreads();
#pragma unroll
        for (int k = 0; k < BK; k++) {
            float a[TM], b[TN];
            *(float4*)&a[0] = *(const float4*)&As[k][ty * TM];
            *(float4*)&a[4] = *(const float4*)&As[k][ty * TM + 4];
            *(float4*)&b[0] = *(const float4*)&Bs[k][tx * TN];
            *(float4*)&b[4] = *(const float4*)&Bs[k][tx * TN + 4];
#pragma unroll
            for (int i = 0; i < TM; i++)
#pragma unroll
                for (int j = 0; j < TN; j++)
                    acc[i][j] = fmaf(a[i], b[j], acc[i][j]);
        }
        __syncthreads();
    }
#pragma unroll
    for (int i = 0; i < TM; i++) {
        const int row = bm + ty * TM + i;
#pragma unroll
        for (int j = 0; j < TN; j += 4) {
            const int col = bn + tx * TN + j;
            float4 v;
            v.x = acc[i][j + 0]; v.y = acc[i][j + 1];
            v.z = acc[i][j + 2]; v.w = acc[i][j + 3];
            if (BIAS) {
                v.x += bias[col + 0]; v.y += bias[col + 1];
                v.z += bias[col + 2]; v.w += bias[col + 3];
            }
            if (RELU) {
                v.x = fmaxf(v.x, 0.f); v.y = fmaxf(v.y, 0.f);
                v.z = fmaxf(v.z, 0.f); v.w = fmaxf(v.w, 0.f);
            }
            *(float4*)&C[(long long)row * N + col] = v;
        }
    }
}

__global__ void softmax_k(float* __restrict__ S)
{
    const long long row = blockIdx.x;
    float* r = S + row * (long long)LQ_N;
    const int t = threadIdx.x;
    float4 v = ((float4*)r)[t];
    float m = fmaxf(fmaxf(v.x, v.y), fmaxf(v.z, v.w));
#pragma unroll
    for (int off = 32; off > 0; off >>= 1)
        m = fmaxf(m, __shfl_xor(m, off));
    __shared__ float red[4];
    const int lane = t & 63, wid = t >> 6;
    if (lane == 0) red[wid] = m;
    __syncthreads();
    m = fmaxf(fmaxf(red[0], red[1]), fmaxf(red[2], red[3]));
    __syncthreads();
    v.x = __expf(v.x - m); v.y = __expf(v.y - m);
    v.z = __expf(v.z - m); v.w = __expf(v.w - m);
    float s = v.x + v.y + v.z + v.w;
#pragma unroll
    for (int off = 32; off > 0; off >>= 1)
        s += __shfl_xor(s, off);
    if (lane == 0) red[wid] = s;
    __syncthreads();
    s = red[0] + red[1] + red[2] + red[3];
    const float inv = 1.0f / s;
    v.x *= inv; v.y *= inv; v.z *= inv; v.w *= inv;
    ((float4*)r)[t] = v;
}

extern "C" void kernel_launch(void* const* d_in, const int* in_sizes, int n_in,
                              void* d_out, int out_size, void* d_ws, size_t ws_size,
                              hipStream_t stream)
{
    const float* p    = (const float*)d_in[0];
    const float* q    = (const float*)d_in[1];
    const float* W    = (const float*)d_in[2];
    const float* bias = (const float*)d_in[3];
    float* out = (float*)d_out;

    const size_t MB32 = 33554432ull;                 // 16M fp16
    const size_t NEED = 5 * MB32 + 2097152ull;       // 160 MB + 2 MB

    if (ws_size >= NEED) {
        char* w = (char*)d_ws;
        u16* p16   = (u16*)(w + 0 * MB32);
        u16* q_hi  = (u16*)(w + 1 * MB32);
        u16* q_lo  = (u16*)(w + 2 * MB32);
        u16* keys  = (u16*)(w + 3 * MB32);
        u16* qT    = (u16*)(w + 4 * MB32);
        u16* Wt    = (u16*)(w + 5 * MB32);
        float* scores = (float*)(w + 1 * MB32);  // reuses q_hi/q_lo after GEMM1
        u16* attn     = (u16*)(w + 0 * MB32);    // reuses p16 after GEMM2

        const long long n4 = (long long)B_N * LQ_N * H_N / 4;
        cvt_f16<<<dim3((unsigned)(n4 / 256)), 256, 0, stream>>>(p, p16, n4);
        fuse_cvt_q<<<dim3(32, 32, B_N), dim3(32, 8), 0, stream>>>(q, q_hi, q_lo, qT);
        transpose_cvt_w<<<dim3(32, 32, 1), dim3(32, 8), 0, stream>>>(W, Wt);

        // keys = (q_hi + q_lo) @ Wt + b : 2 terms, fp16-single keys out.
        gemm2t<true, 1><<<256, 512, 0, stream>>>(
            q_hi, q_lo, Wt, bias, nullptr, keys,
            H_N, /*gn=*/4, /*gmn=*/256, 0, 0, 0);

        // scores[b] = p16[b] @ keys[b]^T : 1 term dense, fp32 out.
        gemm2t<false, 0><<<256, 512, 0, stream>>>(
            p16, p16, keys, nullptr, scores, nullptr,
            LQ_N, /*gn=*/4, /*gmn=*/16,
            (long long)LP_N * H_N, (long long)LQ_N * H_N, (long long)LP_N * LQ_N);

        softmax_f16<<<B_N * LP_N, 256, 0, stream>>>(scores, attn);

        // out[b] = relu(attn[b] @ q[b]) : dense fp16.
        gemm2t<false, 2><<<256, 512, 0, stream>>>(
            attn, attn, qT, nullptr, out, nullptr,
            H_N, /*gn=*/4, /*gmn=*/16,
            (long long)LP_N * LQ_N, (long long)H_N * LQ_N, (long long)LP_N * H_N);
    } else {
        float* keys   = (float*)d_ws;
        float* scores = keys + (long long)B_N * LQ_N * H_N;

        gemm_k<false, true, false><<<dim3(H_N / BN, (B_N * LQ_N) / BM, 1), 256, 0, stream>>>(
            q, W, bias, keys, B_N * LQ_N, H_N, H_N, 0, 0, 0);
        gemm_k<true, false, false><<<dim3(LQ_N / BN, LP_N / BM, B_N), 256, 0, stream>>>(
            p, keys, nullptr, scores, LP_N, LQ_N, H_N,
            (long long)LP_N * H_N, (long long)LQ_N * H_N, (long long)LP_N * LQ_N);
        softmax_k<<<B_N * LP_N, 256, 0, stream>>>(scores);
        gemm_k<false, false, true><<<dim3(H_N / BN, LP_N / BM, B_N), 256, 0, stream>>>(
            scores, q, nullptr, out, LP_N, H_N, LQ_N,
            (long long)LP_N * LQ_N, (long long)LQ_N * H_N, (long long)LP_N * H_N);
    }
}